// Round 9
// baseline (170.901 us; speedup 1.0000x reference)
//
#include <hip/hip_runtime.h>
#include <hip/hip_bf16.h>

typedef __attribute__((ext_vector_type(8))) short short8;       // 8 x bf16 (4 VGPR)
typedef __attribute__((ext_vector_type(4))) float f32x4;        // MFMA acc / float4
typedef __attribute__((ext_vector_type(2))) float f32x2;
typedef __attribute__((ext_vector_type(4))) unsigned short ushort4v;
typedef __attribute__((ext_vector_type(2))) unsigned int uint32x2;

__device__ __forceinline__ unsigned short f2bf(float f) {
    __hip_bfloat16 h = __float2bfloat16(f);
    return __builtin_bit_cast(unsigned short, h);
}
__device__ __forceinline__ unsigned int pack2(float a, float b) {
    return (unsigned int)f2bf(a) | ((unsigned int)f2bf(b) << 16);
}
__device__ __forceinline__ void gload_lds16(const void* g, void* l) {
    __builtin_amdgcn_global_load_lds((const __attribute__((address_space(1))) unsigned int*)g,
                                     (__attribute__((address_space(3))) unsigned int*)l, 16, 0, 0);
}

#define VMCNT(N) asm volatile("s_waitcnt vmcnt(" #N ")" ::: "memory")
#define LGKM0()  asm volatile("s_waitcnt lgkmcnt(0)" ::: "memory")

// ---------------- K0: W fp32 [256][512] -> wt bf16 tiled+bank-swizzled ----------------
// Slot (u=k>>3, c): byte off = ((u*256+c)*16) ^ ((u&3)<<4). Tile kt = bytes [kt*16384,+16384).
__global__ __launch_bounds__(256) void k0_wt(const float* __restrict__ w,
                                             unsigned short* __restrict__ wt) {
    int T = blockIdx.x * 256 + threadIdx.x;     // 0..16383 slots
    int c = T & 255, u = T >> 8;
    const float* s = w + c * 512 + u * 8;
    f32x4 a = *(const f32x4*)s;
    f32x4 b = *(const f32x4*)(s + 4);
    short8 o;
    o[0] = (short)f2bf(a[0]); o[1] = (short)f2bf(a[1]);
    o[2] = (short)f2bf(a[2]); o[3] = (short)f2bf(a[3]);
    o[4] = (short)f2bf(b[0]); o[5] = (short)f2bf(b[1]);
    o[6] = (short)f2bf(b[2]); o[7] = (short)f2bf(b[3]);
    size_t off = (size_t)(((u * 256 + c) * 16) ^ ((u & 3) << 4));
    *(short8*)((char*)wt + off) = o;
}

// ---------------- K1: Q-GEMM + normalize, 64-token blocks, 3 blocks/CU, counted pipeline ----
// grid: 128 windows * 16 token-blocks. block = 256 thr (4 waves), 12 waves/CU.
// Invariant at iter top: outstanding VMEM = 4 B-loads(kt+1).
//   DMA A(kt+1)[4] -> MFMA(kt) -> WRITE_B(kt+1) [auto vmcnt(4)] -> sched_barrier ->
//   LOAD_B(kt+2)[4] -> VMCNT(4) (DMA done, B-loads in flight) -> LGKM -> barrier.
__global__ __launch_bounds__(256, 3) void k1_qgemm(const float* __restrict__ x,
                                                   const unsigned short* __restrict__ wt,
                                                   unsigned short* __restrict__ qn) {
    const int blk = blockIdx.x;
    const int win = blk >> 4;
    const int t0  = (blk & 15) << 6;
    const int b_  = win >> 2;
    const int h0  = ((win >> 1) & 1) << 5;
    const int w0  = (win & 1) << 5;

    __shared__ __align__(16) unsigned short lA[2][4 * 256 * 8];  // 2x16KB DMA image (swz in data)
    __shared__ __align__(16) unsigned short lB[2][64][40];       // 2x5KB [t][k], 80B rows
    __shared__ float nbuf[4][64];                                // 1KB

    const int tid  = threadIdx.x;
    const int lane = tid & 63;
    const int wv   = tid >> 6;
    const int lo   = lane & 15;
    const int hi   = lane >> 4;

    f32x4 acc[4][4];
#pragma unroll
    for (int mi = 0; mi < 4; ++mi)
#pragma unroll
        for (int ni = 0; ni < 4; ++ni) acc[mi][ni] = (f32x4){0.f, 0.f, 0.f, 0.f};

    const float* xblk = x + (size_t)b_ * 512 * 4096 + (size_t)(h0 + (t0 >> 5)) * 64 + w0;
    const int tp  = tid & 31;                 // token-pair 0..31
    const int cg  = tid >> 5;                 // k-group of 4 (0..7)
    const int tt  = tp * 2;
    const int pos = ((tt >> 5) << 6) + (tt & 31);
    const float* xpbase = xblk + (size_t)(cg * 4) * 4096 + pos;

    f32x2 bregs[4];

#define K1_ISSUE_A(KT, BUF)                                                        \
    {                                                                              \
        const char* src_ = (const char*)wt + (size_t)(KT) * 16384;                 \
        char* dst_ = (char*)lA[BUF];                                               \
        _Pragma("unroll")                                                          \
        for (int r_ = 0; r_ < 4; ++r_) {                                           \
            int idx_ = (r_ * 256 + tid) * 16;                                      \
            gload_lds16(src_ + idx_, dst_ + idx_);                                 \
        }                                                                          \
    }
#define K1_LOAD_B(KT)                                                              \
    {                                                                              \
        const float* xp_ = xpbase + (size_t)(KT) * 32 * 4096;                      \
        _Pragma("unroll")                                                          \
        for (int i_ = 0; i_ < 4; ++i_) bregs[i_] = *(const f32x2*)(xp_ + (size_t)i_ * 4096); \
    }
#define K1_WRITE_B(BUF)                                                            \
    {                                                                              \
        ushort4v e0_ = {f2bf(bregs[0][0]), f2bf(bregs[1][0]), f2bf(bregs[2][0]), f2bf(bregs[3][0])}; \
        ushort4v e1_ = {f2bf(bregs[0][1]), f2bf(bregs[1][1]), f2bf(bregs[2][1]), f2bf(bregs[3][1])}; \
        *(ushort4v*)&lB[BUF][tt][cg * 4]     = e0_;                                \
        *(ushort4v*)&lB[BUF][tt + 1][cg * 4] = e1_;                                \
    }

    // prologue
    K1_ISSUE_A(0, 0);
    K1_LOAD_B(0);
    K1_WRITE_B(0);      // auto vmcnt(0): drains DMA(0) too (prologue only)
    K1_LOAD_B(1);
    LGKM0();
    __builtin_amdgcn_s_barrier();

    for (int kt = 0; kt < 16; ++kt) {
        const int b = kt & 1;
        // 1. DMA next A tile into lA[b^1]
        {
            const int ktn = (kt + 1 < 16) ? kt + 1 : 15;
            K1_ISSUE_A(ktn, b ^ 1);
        }
        // 2. compute current tile
        short8 af[4], bfr[4];
#pragma unroll
        for (int mi = 0; mi < 4; ++mi) {
            int base = (hi * 256 + wv * 64 + mi * 16 + lo) * 16;   // bytes
            af[mi] = *(const short8*)((char*)lA[b] + (base ^ ((hi & 3) << 4)));
        }
#pragma unroll
        for (int ni = 0; ni < 4; ++ni)
            bfr[ni] = *(const short8*)&lB[b][ni * 16 + lo][hi * 8];
        __builtin_amdgcn_s_setprio(1);
#pragma unroll
        for (int mi = 0; mi < 4; ++mi)
#pragma unroll
            for (int ni = 0; ni < 4; ++ni)
                acc[mi][ni] = __builtin_amdgcn_mfma_f32_16x16x32_bf16(af[mi], bfr[ni], acc[mi][ni], 0, 0, 0);
        __builtin_amdgcn_s_setprio(0);
        // 3. write next B (bregs ~1 iter old; auto-wait = vmcnt(4), DMA stays in flight)
        K1_WRITE_B(b ^ 1);
        // 4. pin VMEM order across the next issue
        __builtin_amdgcn_sched_barrier(0);
        // 5. issue B loads for kt+2
        {
            const int ktn2 = (kt + 2 < 16) ? kt + 2 : 15;
            K1_LOAD_B(ktn2);
        }
        // 6. wait: 4 DMA done (4 younger B-loads in flight); publish lB writes
        VMCNT(4);
        LGKM0();
        __builtin_amdgcn_s_barrier();
    }
    VMCNT(0);   // drain tail prefetches

    // ---- per-token norm over c ----
    float part[4];
#pragma unroll
    for (int ni = 0; ni < 4; ++ni) {
        float s = 0.f;
#pragma unroll
        for (int mi = 0; mi < 4; ++mi)
#pragma unroll
            for (int r = 0; r < 4; ++r) s += acc[mi][ni][r] * acc[mi][ni][r];
        s += __shfl_xor(s, 16);
        s += __shfl_xor(s, 32);
        part[ni] = s;
    }
    if (hi == 0) {
#pragma unroll
        for (int ni = 0; ni < 4; ++ni) nbuf[wv][ni * 16 + lo] = part[ni];
    }
    __syncthreads();

    char* qwin_out = (char*)(qn + (size_t)win * 1024 * 256);
#pragma unroll
    for (int ni = 0; ni < 4; ++ni) {
        const int tl = ni * 16 + lo;
        float s = nbuf[0][tl] + nbuf[1][tl] + nbuf[2][tl] + nbuf[3][tl];
        float inv = 1.f / (sqrtf(s) + 1e-6f);
        const int rq = t0 + tl;
        const int swz = (rq & 7) << 4;
#pragma unroll
        for (int mi = 0; mi < 4; ++mi) {
            int c = wv * 64 + mi * 16 + hi * 4;
            ushort4v o = {f2bf(acc[mi][ni][0] * inv), f2bf(acc[mi][ni][1] * inv),
                          f2bf(acc[mi][ni][2] * inv), f2bf(acc[mi][ni][3] * inv)};
            size_t off = ((size_t)rq * 512 + (size_t)(c * 2)) ^ (size_t)swz;
            *(ushort4v*)(qwin_out + off) = o;
        }
    }
}

// ---------------- K2: S^T = K Q^T, relu, packed P, PV (R8 verbatim) ----------------
// grid: 512 = 128 windows * 4 query-blocks (256 q each); bid&127 = window (XCD swizzle).
__global__ __launch_bounds__(256, 2) void k2_attn(const unsigned short* __restrict__ qn,
                                                  const float* __restrict__ v,
                                                  float* __restrict__ out) {
    const int g   = blockIdx.x;
    const int win = g & 127;
    const int qb  = g >> 7;
    const int b_  = win >> 2;
    const int h0  = ((win >> 1) & 1) << 5;
    const int w0  = (win & 1) << 5;

    __shared__ __align__(16) unsigned short lK[64 * 256];   // swizzled key image, 32 KB
    __shared__ __align__(16) unsigned short lP[256][72];    // P [q][key], 36 KB, wave-private rows
    __shared__ __align__(16) unsigned short lV[16][72];     // V^T [ch][key], row15 = ones

    const int tid  = threadIdx.x;
    const int lane = tid & 63;
    const int wv   = tid >> 6;
    const int lo   = lane & 15;
    const int hi   = lane >> 4;

    const char* qwin = (const char*)(qn + (size_t)win * 1024 * 256);
    const int qw0 = qb * 256 + wv * 64;

    short8 qa[4][8];
#pragma unroll
    for (int mi = 0; mi < 4; ++mi) {
        const int rq = qw0 + mi * 16 + lo;
        const size_t swz = (size_t)((rq & 7) << 4);
#pragma unroll
        for (int kc = 0; kc < 8; ++kc)
            qa[mi][kc] = *(const short8*)(qwin + (((size_t)rq * 512 + kc * 64 + hi * 16) ^ swz));
    }

    f32x4 accout[4];
#pragma unroll
    for (int t = 0; t < 4; ++t) accout[t] = (f32x4){0.f, 0.f, 0.f, 0.f};

    const float* vbase = v + (size_t)b_ * 15 * 4096 + (size_t)h0 * 64 + w0;
    char* lKb = (char*)lK;
    char* lPb = (char*)&lP[0][0];
    char* lVb = (char*)&lV[0][0];

    for (int chk = 0; chk < 16; ++chk) {
        const int kbase = chk << 6;
        __syncthreads();
        {
            const char* src = qwin + (size_t)kbase * 512;
#pragma unroll
            for (int r = 0; r < 8; ++r) {
                int idx = (r * 256 + tid) * 16;
                gload_lds16(src + idx, lKb + idx);
            }
        }
        {
            const int chn = tid & 15;
            const int kp  = tid >> 4;
            uint32x2 u;
            if (chn < 15) {
                int jk = kbase + kp * 4;
                const float* vp = vbase + (size_t)chn * 4096 + ((jk >> 5) * 64 + (jk & 31));
                f32x4 d = *(const f32x4*)vp;
                u[0] = pack2(d[0], d[1]);
                u[1] = pack2(d[2], d[3]);
            } else {
                u[0] = 0x3F803F80u;
                u[1] = 0x3F803F80u;
            }
            *(uint32x2*)(lVb + chn * 144 + kp * 8) = u;
        }
        __syncthreads();

#pragma unroll
        for (int ni = 0; ni < 4; ++ni) {
            f32x4 st[4];
#pragma unroll
            for (int mi = 0; mi < 4; ++mi) st[mi] = (f32x4){0.f, 0.f, 0.f, 0.f};
            __builtin_amdgcn_s_setprio(1);
#pragma unroll
            for (int kc = 0; kc < 8; ++kc) {
                const int row = ni * 16 + lo;
                const int off = ((row * 512) + kc * 64 + hi * 16) ^ ((row & 7) << 4);
                short8 kb = *(const short8*)(lKb + off);
#pragma unroll
                for (int mi = 0; mi < 4; ++mi)
                    st[mi] = __builtin_amdgcn_mfma_f32_16x16x32_bf16(kb, qa[mi][kc], st[mi], 0, 0, 0);
            }
            __builtin_amdgcn_s_setprio(0);
#pragma unroll
            for (int mi = 0; mi < 4; ++mi) {
                uint32x2 u;
                u[0] = pack2(fmaxf(st[mi][0], 0.f), fmaxf(st[mi][1], 0.f));
                u[1] = pack2(fmaxf(st[mi][2], 0.f), fmaxf(st[mi][3], 0.f));
                *(uint32x2*)(lPb + (wv * 64 + mi * 16 + lo) * 144 + ni * 32 + hi * 8) = u;
            }
        }

        __builtin_amdgcn_s_setprio(1);
#pragma unroll
        for (int t = 0; t < 4; ++t) {
#pragma unroll
            for (int ks = 0; ks < 2; ++ks) {
                short8 pa  = *(const short8*)(lPb + (wv * 64 + t * 16 + lo) * 144 + ks * 64 + hi * 16);
                short8 vbf = *(const short8*)(lVb + lo * 144 + ks * 64 + hi * 16);
                accout[t] = __builtin_amdgcn_mfma_f32_16x16x32_bf16(pa, vbf, accout[t], 0, 0, 0);
            }
        }
        __builtin_amdgcn_s_setprio(0);
    }

#pragma unroll
    for (int t = 0; t < 4; ++t) {
#pragma unroll
        for (int r = 0; r < 4; ++r) {
            float rs = __shfl(accout[t][r], (lane & 48) | 15);
            if (lo < 15) {
                int q = qw0 + t * 16 + hi * 4 + r;
                out[(size_t)(b_ * 15 + lo) * 4096 + (size_t)(h0 + (q >> 5)) * 64 + (w0 + (q & 31))] =
                    accout[t][r] / (rs + 1e-6f);
            }
        }
    }
}

extern "C" void kernel_launch(void* const* d_in, const int* in_sizes, int n_in,
                              void* d_out, int out_size, void* d_ws, size_t ws_size,
                              hipStream_t stream) {
    const float* x = (const float*)d_in[0];
    const float* v = (const float*)d_in[1];
    const float* w = (const float*)d_in[2];
    float* out = (float*)d_out;

    unsigned short* qn = (unsigned short*)d_ws;                          // 64 MiB (swizzled)
    unsigned short* wt = (unsigned short*)((char*)d_ws + (size_t)128 * 1024 * 256 * 2);  // 256 KiB tiled W

    k0_wt<<<64, 256, 0, stream>>>(w, wt);
    k1_qgemm<<<2048, 256, 0, stream>>>(x, wt, qn);
    k2_attn<<<512, 256, 0, stream>>>(qn, v, out);
}

// Round 10
// 153.448 us; speedup vs baseline: 1.1137x; 1.1137x over previous
//
#include <hip/hip_runtime.h>
#include <hip/hip_bf16.h>

typedef __attribute__((ext_vector_type(8))) short short8;       // 8 x bf16 (4 VGPR)
typedef __attribute__((ext_vector_type(4))) float f32x4;        // MFMA acc / float4
typedef __attribute__((ext_vector_type(2))) float f32x2;
typedef __attribute__((ext_vector_type(4))) unsigned short ushort4v;
typedef __attribute__((ext_vector_type(2))) unsigned int uint32x2;

__device__ __forceinline__ unsigned short f2bf(float f) {
    __hip_bfloat16 h = __float2bfloat16(f);
    return __builtin_bit_cast(unsigned short, h);
}
__device__ __forceinline__ unsigned int pack2(float a, float b) {
    return (unsigned int)f2bf(a) | ((unsigned int)f2bf(b) << 16);
}
__device__ __forceinline__ void gload_lds16(const void* g, void* l) {
    __builtin_amdgcn_global_load_lds((const __attribute__((address_space(1))) unsigned int*)g,
                                     (__attribute__((address_space(3))) unsigned int*)l, 16, 0, 0);
}

#define VMCNT(N) asm volatile("s_waitcnt vmcnt(" #N ")" ::: "memory")
#define LGKM0()  asm volatile("s_waitcnt lgkmcnt(0)" ::: "memory")

// ---------------- K0: W fp32 [256][512] -> wt bf16 tiled+bank-swizzled ----------------
// Slot (u=k>>3, c): byte off = ((u*256+c)*16) ^ ((u&3)<<4). Tile kt = bytes [kt*16384,+16384).
__global__ __launch_bounds__(256) void k0_wt(const float* __restrict__ w,
                                             unsigned short* __restrict__ wt) {
    int T = blockIdx.x * 256 + threadIdx.x;     // 0..16383 slots
    int c = T & 255, u = T >> 8;
    const float* s = w + c * 512 + u * 8;
    f32x4 a = *(const f32x4*)s;
    f32x4 b = *(const f32x4*)(s + 4);
    short8 o;
    o[0] = (short)f2bf(a[0]); o[1] = (short)f2bf(a[1]);
    o[2] = (short)f2bf(a[2]); o[3] = (short)f2bf(a[3]);
    o[4] = (short)f2bf(b[0]); o[5] = (short)f2bf(b[1]);
    o[6] = (short)f2bf(b[2]); o[7] = (short)f2bf(b[3]);
    size_t off = (size_t)(((u * 256 + c) * 16) ^ ((u & 3) << 4));
    *(short8*)((char*)wt + off) = o;
}

// ---------------- K1: Q-GEMM + normalize, row-contiguous window-pair blocks ----------------
// grid: 1024 = 32 b * 2 wh * 16 rb. Block covers 2 full rows x 64 w (BOTH windows of the
// h-row pair) = 128 tokens whose x bytes are 512B-contiguous per channel.
// Token f (0..127): rho=f>>6 (row), w=f&63; window ww=(f>>5)&1; rq=64*rb+32*rho+(w&31).
// Pipeline identical to R8: DMA A(kt+1) -> MFMA(kt) -> WRITE_B(kt+1) [auto vmcnt(4)] ->
// sched_barrier -> LOAD_B(kt+2)[8] -> VMCNT(8) -> LGKM -> barrier.
__global__ __launch_bounds__(256, 2) void k1_qgemm(const float* __restrict__ x,
                                                   const unsigned short* __restrict__ wt,
                                                   unsigned short* __restrict__ qn) {
    const int blk = blockIdx.x;
    const int b_  = blk >> 5;
    const int wh  = (blk >> 4) & 1;
    const int rb  = blk & 15;
    const int winbase = b_ * 4 + wh * 2;

    __shared__ __align__(16) unsigned short lA[2][4 * 256 * 8];  // 2x16KB DMA image (swz in data)
    __shared__ __align__(16) unsigned short lB[2][128][40];      // 2x10KB [f][k], 80B rows
    __shared__ float nbuf[4][128];

    const int tid  = threadIdx.x;
    const int lane = tid & 63;
    const int wv   = tid >> 6;
    const int lo   = lane & 15;
    const int hi   = lane >> 4;

    f32x4 acc[4][8];
#pragma unroll
    for (int mi = 0; mi < 4; ++mi)
#pragma unroll
        for (int ni = 0; ni < 8; ++ni) acc[mi][ni] = (f32x4){0.f, 0.f, 0.f, 0.f};

    // x slab: rows wh*32 + 2rb, +1 (global h), all 64 w
    const float* xslab = x + (size_t)b_ * 512 * 4096 + (size_t)(wh * 32 + rb * 2) * 64;
    const int tp  = tid & 63;     // token-pair: tokens 2tp, 2tp+1 (f-order)
    const int cg  = tid >> 6;     // channel slab (= wv): channels cg*8 .. +7
    const int tt  = tp * 2;
    const float* xpbase = xslab + (size_t)(cg * 8) * 4096 + tt;

    f32x2 bregs[8];

#define K1_ISSUE_A(KT, BUF)                                                        \
    {                                                                              \
        const char* src_ = (const char*)wt + (size_t)(KT) * 16384;                 \
        char* dst_ = (char*)lA[BUF];                                               \
        _Pragma("unroll")                                                          \
        for (int r_ = 0; r_ < 4; ++r_) {                                           \
            int idx_ = (r_ * 256 + tid) * 16;                                      \
            gload_lds16(src_ + idx_, dst_ + idx_);                                 \
        }                                                                          \
    }
#define K1_LOAD_B(KT)                                                              \
    {                                                                              \
        const float* xp_ = xpbase + (size_t)(KT) * 32 * 4096;                      \
        _Pragma("unroll")                                                          \
        for (int i_ = 0; i_ < 8; ++i_) bregs[i_] = *(const f32x2*)(xp_ + (size_t)i_ * 4096); \
    }
#define K1_WRITE_B(BUF)                                                            \
    {                                                                              \
        short8 v0_, v1_;                                                           \
        _Pragma("unroll")                                                          \
        for (int i_ = 0; i_ < 8; ++i_) {                                           \
            v0_[i_] = (short)f2bf(bregs[i_][0]);                                   \
            v1_[i_] = (short)f2bf(bregs[i_][1]);                                   \
        }                                                                          \
        *(short8*)&lB[BUF][tt][cg * 8]     = v0_;                                  \
        *(short8*)&lB[BUF][tt + 1][cg * 8] = v1_;                                  \
    }

    // prologue
    K1_ISSUE_A(0, 0);
    K1_LOAD_B(0);
    K1_WRITE_B(0);      // auto vmcnt(0): drains DMA(0) too (prologue only)
    K1_LOAD_B(1);
    LGKM0();
    __builtin_amdgcn_s_barrier();

    for (int kt = 0; kt < 16; ++kt) {
        const int b = kt & 1;
        // 1. DMA next A tile into lA[b^1]
        {
            const int ktn = (kt + 1 < 16) ? kt + 1 : 15;
            K1_ISSUE_A(ktn, b ^ 1);
        }
        // 2. compute current tile
        short8 af[4], bfr[8];
#pragma unroll
        for (int mi = 0; mi < 4; ++mi) {
            int base = (hi * 256 + wv * 64 + mi * 16 + lo) * 16;   // bytes
            af[mi] = *(const short8*)((char*)lA[b] + (base ^ ((hi & 3) << 4)));
        }
#pragma unroll
        for (int ni = 0; ni < 8; ++ni)
            bfr[ni] = *(const short8*)&lB[b][ni * 16 + lo][hi * 8];
        __builtin_amdgcn_s_setprio(1);
#pragma unroll
        for (int mi = 0; mi < 4; ++mi)
#pragma unroll
            for (int ni = 0; ni < 8; ++ni)
                acc[mi][ni] = __builtin_amdgcn_mfma_f32_16x16x32_bf16(af[mi], bfr[ni], acc[mi][ni], 0, 0, 0);
        __builtin_amdgcn_s_setprio(0);
        // 3. write next B (bregs ~1 iter old; auto-wait = vmcnt(4), DMA stays in flight)
        K1_WRITE_B(b ^ 1);
        // 4. pin VMEM order across the next issue
        __builtin_amdgcn_sched_barrier(0);
        // 5. issue B loads for kt+2
        {
            const int ktn2 = (kt + 2 < 16) ? kt + 2 : 15;
            K1_LOAD_B(ktn2);
        }
        // 6. wait: 4 DMA done (8 younger B-loads in flight); publish lB writes
        VMCNT(8);
        LGKM0();
        __builtin_amdgcn_s_barrier();
    }
    VMCNT(0);   // drain tail prefetches

    // ---- per-token norm over c ----
    float part[8];
#pragma unroll
    for (int ni = 0; ni < 8; ++ni) {
        float s = 0.f;
#pragma unroll
        for (int mi = 0; mi < 4; ++mi)
#pragma unroll
            for (int r = 0; r < 4; ++r) s += acc[mi][ni][r] * acc[mi][ni][r];
        s += __shfl_xor(s, 16);
        s += __shfl_xor(s, 32);
        part[ni] = s;
    }
    if (hi == 0) {
#pragma unroll
        for (int ni = 0; ni < 8; ++ni) nbuf[wv][ni * 16 + lo] = part[ni];
    }
    __syncthreads();

#pragma unroll
    for (int ni = 0; ni < 8; ++ni) {
        const int tl = ni * 16 + lo;     // token f
        float s = nbuf[0][tl] + nbuf[1][tl] + nbuf[2][tl] + nbuf[3][tl];
        float inv = 1.f / (sqrtf(s) + 1e-6f);
        const int f0  = ni * 16;
        const int ww  = (f0 >> 5) & 1;
        const int rho = f0 >> 6;
        const int rq  = rb * 64 + rho * 32 + (f0 & 31) + lo;
        char* qwin_out = (char*)qn + (size_t)(winbase + ww) * (1024 * 256 * 2);
        const int swz = (rq & 7) << 4;
#pragma unroll
        for (int mi = 0; mi < 4; ++mi) {
            int c = wv * 64 + mi * 16 + hi * 4;
            ushort4v o = {f2bf(acc[mi][ni][0] * inv), f2bf(acc[mi][ni][1] * inv),
                          f2bf(acc[mi][ni][2] * inv), f2bf(acc[mi][ni][3] * inv)};
            size_t off = ((size_t)rq * 512 + (size_t)(c * 2)) ^ (size_t)swz;
            *(ushort4v*)(qwin_out + off) = o;
        }
    }
}

// ---------------- K2: S^T = K Q^T, relu, packed P, PV (R8 verbatim) ----------------
// grid: 512 = 128 windows * 4 query-blocks (256 q each); bid&127 = window (XCD swizzle).
__global__ __launch_bounds__(256, 2) void k2_attn(const unsigned short* __restrict__ qn,
                                                  const float* __restrict__ v,
                                                  float* __restrict__ out) {
    const int g   = blockIdx.x;
    const int win = g & 127;
    const int qb  = g >> 7;
    const int b_  = win >> 2;
    const int h0  = ((win >> 1) & 1) << 5;
    const int w0  = (win & 1) << 5;

    __shared__ __align__(16) unsigned short lK[64 * 256];   // swizzled key image, 32 KB
    __shared__ __align__(16) unsigned short lP[256][72];    // P [q][key], 36 KB, wave-private rows
    __shared__ __align__(16) unsigned short lV[16][72];     // V^T [ch][key], row15 = ones

    const int tid  = threadIdx.x;
    const int lane = tid & 63;
    const int wv   = tid >> 6;
    const int lo   = lane & 15;
    const int hi   = lane >> 4;

    const char* qwin = (const char*)(qn + (size_t)win * 1024 * 256);
    const int qw0 = qb * 256 + wv * 64;

    short8 qa[4][8];
#pragma unroll
    for (int mi = 0; mi < 4; ++mi) {
        const int rq = qw0 + mi * 16 + lo;
        const size_t swz = (size_t)((rq & 7) << 4);
#pragma unroll
        for (int kc = 0; kc < 8; ++kc)
            qa[mi][kc] = *(const short8*)(qwin + (((size_t)rq * 512 + kc * 64 + hi * 16) ^ swz));
    }

    f32x4 accout[4];
#pragma unroll
    for (int t = 0; t < 4; ++t) accout[t] = (f32x4){0.f, 0.f, 0.f, 0.f};

    const float* vbase = v + (size_t)b_ * 15 * 4096 + (size_t)h0 * 64 + w0;
    char* lKb = (char*)lK;
    char* lPb = (char*)&lP[0][0];
    char* lVb = (char*)&lV[0][0];

    for (int chk = 0; chk < 16; ++chk) {
        const int kbase = chk << 6;
        __syncthreads();
        {
            const char* src = qwin + (size_t)kbase * 512;
#pragma unroll
            for (int r = 0; r < 8; ++r) {
                int idx = (r * 256 + tid) * 16;
                gload_lds16(src + idx, lKb + idx);
            }
        }
        {
            const int chn = tid & 15;
            const int kp  = tid >> 4;
            uint32x2 u;
            if (chn < 15) {
                int jk = kbase + kp * 4;
                const float* vp = vbase + (size_t)chn * 4096 + ((jk >> 5) * 64 + (jk & 31));
                f32x4 d = *(const f32x4*)vp;
                u[0] = pack2(d[0], d[1]);
                u[1] = pack2(d[2], d[3]);
            } else {
                u[0] = 0x3F803F80u;
                u[1] = 0x3F803F80u;
            }
            *(uint32x2*)(lVb + chn * 144 + kp * 8) = u;
        }
        __syncthreads();

#pragma unroll
        for (int ni = 0; ni < 4; ++ni) {
            f32x4 st[4];
#pragma unroll
            for (int mi = 0; mi < 4; ++mi) st[mi] = (f32x4){0.f, 0.f, 0.f, 0.f};
            __builtin_amdgcn_s_setprio(1);
#pragma unroll
            for (int kc = 0; kc < 8; ++kc) {
                const int row = ni * 16 + lo;
                const int off = ((row * 512) + kc * 64 + hi * 16) ^ ((row & 7) << 4);
                short8 kb = *(const short8*)(lKb + off);
#pragma unroll
                for (int mi = 0; mi < 4; ++mi)
                    st[mi] = __builtin_amdgcn_mfma_f32_16x16x32_bf16(kb, qa[mi][kc], st[mi], 0, 0, 0);
            }
            __builtin_amdgcn_s_setprio(0);
#pragma unroll
            for (int mi = 0; mi < 4; ++mi) {
                uint32x2 u;
                u[0] = pack2(fmaxf(st[mi][0], 0.f), fmaxf(st[mi][1], 0.f));
                u[1] = pack2(fmaxf(st[mi][2], 0.f), fmaxf(st[mi][3], 0.f));
                *(uint32x2*)(lPb + (wv * 64 + mi * 16 + lo) * 144 + ni * 32 + hi * 8) = u;
            }
        }

        __builtin_amdgcn_s_setprio(1);
#pragma unroll
        for (int t = 0; t < 4; ++t) {
#pragma unroll
            for (int ks = 0; ks < 2; ++ks) {
                short8 pa  = *(const short8*)(lPb + (wv * 64 + t * 16 + lo) * 144 + ks * 64 + hi * 16);
                short8 vbf = *(const short8*)(lVb + lo * 144 + ks * 64 + hi * 16);
                accout[t] = __builtin_amdgcn_mfma_f32_16x16x32_bf16(pa, vbf, accout[t], 0, 0, 0);
            }
        }
        __builtin_amdgcn_s_setprio(0);
    }

#pragma unroll
    for (int t = 0; t < 4; ++t) {
#pragma unroll
        for (int r = 0; r < 4; ++r) {
            float rs = __shfl(accout[t][r], (lane & 48) | 15);
            if (lo < 15) {
                int q = qw0 + t * 16 + hi * 4 + r;
                out[(size_t)(b_ * 15 + lo) * 4096 + (size_t)(h0 + (q >> 5)) * 64 + (w0 + (q & 31))] =
                    accout[t][r] / (rs + 1e-6f);
            }
        }
    }
}

extern "C" void kernel_launch(void* const* d_in, const int* in_sizes, int n_in,
                              void* d_out, int out_size, void* d_ws, size_t ws_size,
                              hipStream_t stream) {
    const float* x = (const float*)d_in[0];
    const float* v = (const float*)d_in[1];
    const float* w = (const float*)d_in[2];
    float* out = (float*)d_out;

    unsigned short* qn = (unsigned short*)d_ws;                          // 64 MiB (swizzled)
    unsigned short* wt = (unsigned short*)((char*)d_ws + (size_t)128 * 1024 * 256 * 2);  // 256 KiB tiled W

    k0_wt<<<64, 256, 0, stream>>>(w, wt);
    k1_qgemm<<<1024, 256, 0, stream>>>(x, wt, qn);
    k2_attn<<<512, 256, 0, stream>>>(qn, v, out);
}